// Round 3
// baseline (367.063 us; speedup 1.0000x reference)
//
#include <hip/hip_runtime.h>
#include <hip/hip_bf16.h>

#define N_NODES 100000
#define N_EDGES 600000
#define DIM 128
#define EDIM 32

typedef __attribute__((ext_vector_type(8))) short bf16x8;
typedef __attribute__((ext_vector_type(4))) float f32x4;

static __device__ __forceinline__ short f2bf(float v) {
    __hip_bfloat16 h = __float2bfloat16(v);
    return *(short*)&h;
}
static __device__ __forceinline__ float bfu2f(unsigned short u) {
    return __uint_as_float(((unsigned int)u) << 16);
}

// ---------------- workspace layout (bytes) ----------------
#define AGGX_OFF  0ULL                       // bf16 N*128 = 25,600,000
#define AGGE_OFF  25600000ULL                // bf16 N*32  =  6,400,000
#define CSR_OFF   32000000ULL                // int2 E     =  4,800,000
#define OFF_OFF   36800000ULL                // int  N+1   (start offsets)
#define DEG_OFF   37200008ULL                // int  N     (count, then fill-cursor)
#define BSUM_OFF  37600016ULL                // int  128
#define WEW1_OFF  37600528ULL                // f32  32*128 = 16,384
#define XBF_OFF   37617024ULL                // bf16 N*128 = 25,600,000 (optional)
#define WS_NEED_XBF (XBF_OFF + 25600000ULL)
#define SCAN_NBLK 98                         // ceil(100001/1024)

// ===========================================================================
// WeW1 = We @ W1  (32x128 f32). The aggE@We term enters layer 1 as
// aggE @ (We @ W1) by linearity (ReLU is applied after the full sum).
// ===========================================================================
__global__ __launch_bounds__(1024) void compute_wew1(
    const float* __restrict__ We, const float* __restrict__ W1,
    float* __restrict__ wew1) {
    const int idx = blockIdx.x * 1024 + threadIdx.x;   // 4 blocks -> 4096
    const int k = idx >> 7, d2 = idx & 127;
    float a = 0.f;
    #pragma unroll 8
    for (int d = 0; d < DIM; ++d)
        a += We[k * DIM + d] * W1[d * DIM + d2];       // We: uniform; W1: coalesced
    wew1[k * DIM + d2] = a;
}

// ===========================================================================
// x -> bf16 copy (streaming). Halves the per-edge gather footprint in
// gine_aggregate: x-row 512B (4 lines) -> 256B (2 lines).
// ===========================================================================
typedef __attribute__((ext_vector_type(8))) short short8v;
__global__ __launch_bounds__(256) void cast_x_bf16(
    const float* __restrict__ x, unsigned short* __restrict__ xbf) {
    const int total = N_NODES * DIM / 8;               // 1.6M chunks of 8
    for (int i = blockIdx.x * 256 + threadIdx.x; i < total; i += gridDim.x * 256) {
        float4 a = *(const float4*)&x[(size_t)i * 8];
        float4 b = *(const float4*)&x[(size_t)i * 8 + 4];
        short8v o;
        o[0] = f2bf(a.x); o[1] = f2bf(a.y); o[2] = f2bf(a.z); o[3] = f2bf(a.w);
        o[4] = f2bf(b.x); o[5] = f2bf(b.y); o[6] = f2bf(b.z); o[7] = f2bf(b.w);
        *(short8v*)&xbf[(size_t)i * 8] = o;
    }
}

// ===========================================================================
// CSR build
// ===========================================================================
__global__ void count_deg(const int* __restrict__ eidx, int* __restrict__ cnt) {
    int e = blockIdx.x * 256 + threadIdx.x;
    if (e < N_EDGES) atomicAdd(&cnt[eidx[e]], 1);
}

__global__ __launch_bounds__(1024) void scan_blocks(
    const int* __restrict__ cnt, int* __restrict__ off, int* __restrict__ bsum) {
    const int t = blockIdx.x * 1024 + threadIdx.x;
    const int lane = threadIdx.x & 63, wv = threadIdx.x >> 6;
    int v = (t < N_NODES) ? cnt[t] : 0;
    int s = v;
    #pragma unroll
    for (int o = 1; o < 64; o <<= 1) {
        int u = __shfl_up(s, o, 64);
        if (lane >= o) s += u;
    }
    __shared__ int wsum[16];
    if (lane == 63) wsum[wv] = s;
    __syncthreads();
    if (threadIdx.x == 0) {
        int a = 0;
        #pragma unroll
        for (int w = 0; w < 16; ++w) { int tmp = wsum[w]; wsum[w] = a; a += tmp; }
        bsum[blockIdx.x] = a;
    }
    __syncthreads();
    if (t < N_NODES) off[t] = s - v + wsum[wv];
}

// Adds the cross-block prefix (reduced in-kernel from bsum), writes the fill
// cursor copy, sets off[N]=E.
__global__ __launch_bounds__(1024) void scan_add2(
    int* __restrict__ off, int* __restrict__ cursor, const int* __restrict__ bsum) {
    __shared__ int pref;
    const int b = blockIdx.x;
    if (threadIdx.x < 64) {
        int v = 0;
        if ((int)threadIdx.x < b) v = bsum[threadIdx.x];
        const int i2 = threadIdx.x + 64;
        if (i2 < b) v += bsum[i2];
        #pragma unroll
        for (int o = 32; o >= 1; o >>= 1) v += __shfl_down(v, o, 64);
        if (threadIdx.x == 0) pref = v;
    }
    __syncthreads();
    const int t = b * 1024 + threadIdx.x;
    if (t < N_NODES) {
        const int val = off[t] + pref;
        off[t] = val;
        cursor[t] = val;
    } else if (t == N_NODES) {
        off[t] = N_EDGES;
    }
}

// fill via separate cursor array; off[] keeps clean start offsets.
__global__ void csr_fill(const int* __restrict__ eidx, int* __restrict__ cursor,
                         int2* __restrict__ csr) {
    int e = blockIdx.x * 256 + threadIdx.x;
    if (e < N_EDGES) {
        int i = eidx[e];
        int p = atomicAdd(&cursor[i], 1);
        csr[p] = make_int2(e, eidx[N_EDGES + e]);
    }
}

// ===========================================================================
// Aggregate: HALF-WAVE (32 lanes) per node, 8-edge unconditional batch.
// The kernel is line-miss-throughput-bound (~100cy/edge at 5 lines/edge);
// BF=1 gathers a bf16 copy of x (2 lines/row instead of 4) => 3 lines/edge.
// BF=0 is the f32 fallback when the workspace can't hold the bf16 copy.
// ===========================================================================
template <int BF>
__global__ __launch_bounds__(256, 4) void gine_aggregate_t(
    const void* __restrict__ xsrc,
    const float* __restrict__ eattr,
    const int* __restrict__ off,      // N+1 start offsets
    const int2* __restrict__ csr,
    unsigned short* __restrict__ aggX,
    unsigned short* __restrict__ aggE)
{
    const int l5 = threadIdx.x & 31;
    const int nhw = (gridDim.x * 256) >> 5;        // total half-waves
    int n = (blockIdx.x * 256 + threadIdx.x) >> 5; // my first node

    int s = off[n], e = off[n + 1];
    while (true) {
        const int n2 = n + nhw;                    // prefetch next node's extent
        int s2 = 0, e2 = 0;
        if (n2 < N_NODES) { s2 = off[n2]; e2 = off[n2 + 1]; }

        float a0 = 0.f, a1 = 0.f, a2 = 0.f, a3 = 0.f, ae = 0.f;
        for (int t0 = s; t0 < e; t0 += 8) {
            int2 cc[8];
            #pragma unroll
            for (int k = 0; k < 8; ++k)
                cc[k] = csr[min(t0 + k, e - 1)];   // clamped: always valid
            float ev[8];
            if constexpr (BF) {
                const unsigned short* xb = (const unsigned short*)xsrc;
                ushort4 xv[8];
                #pragma unroll
                for (int k = 0; k < 8; ++k) {
                    xv[k] = *(const ushort4*)&xb[(size_t)cc[k].y * DIM + l5 * 4];
                    ev[k] = eattr[(size_t)cc[k].x * EDIM + l5];
                }
                #pragma unroll
                for (int k = 0; k < 8; ++k) {
                    const float msk = (t0 + k < e) ? 1.f : 0.f;
                    a0 += msk * bfu2f(xv[k].x); a1 += msk * bfu2f(xv[k].y);
                    a2 += msk * bfu2f(xv[k].z); a3 += msk * bfu2f(xv[k].w);
                    ae += msk * ev[k];
                }
            } else {
                const float* xf = (const float*)xsrc;
                float4 xv[8];
                #pragma unroll
                for (int k = 0; k < 8; ++k) {
                    xv[k] = *(const float4*)&xf[(size_t)cc[k].y * DIM + l5 * 4];
                    ev[k] = eattr[(size_t)cc[k].x * EDIM + l5];
                }
                #pragma unroll
                for (int k = 0; k < 8; ++k) {
                    const float msk = (t0 + k < e) ? 1.f : 0.f;
                    a0 += msk * xv[k].x; a1 += msk * xv[k].y;
                    a2 += msk * xv[k].z; a3 += msk * xv[k].w;
                    ae += msk * ev[k];
                }
            }
        }
        short4 hv;
        hv.x = f2bf(a0); hv.y = f2bf(a1); hv.z = f2bf(a2); hv.w = f2bf(a3);
        *(short4*)&aggX[(size_t)n * DIM + l5 * 4] = hv;
        aggE[(size_t)n * EDIM + l5] = (unsigned short)f2bf(ae);

        if (n2 >= N_NODES) break;
        n = n2; s = s2; e = e2;
    }
}

// ===========================================================================
// Fused (aggE@WeW1) + MLP1 + MLP2 + LayerNorm, bf16 MFMA 16x16x32.
// hrow = (1+eps)*x + aggX + deg*be; layer1 = hrow@W1 + aggE@(We@W1).
// 1024 threads = 16 waves share W-fragment LDS caches.
// deg is derived as off[n+1]-off[n] (L1-resident).
// ===========================================================================
#define HROW_STRIDE 136

__global__ __launch_bounds__(1024) void gine_mlp_fused(
    const float* __restrict__ x,
    const unsigned short* __restrict__ aggX,
    const unsigned short* __restrict__ aggE,
    const int* __restrict__ off,
    const float* __restrict__ wew1,
    const float* __restrict__ be,
    const float* __restrict__ W1,
    const float* __restrict__ b1,
    const float* __restrict__ W2,
    const float* __restrict__ b2,
    const float* __restrict__ epsp,
    const float* __restrict__ gamma,
    const float* __restrict__ beta,
    float* __restrict__ out)
{
    __shared__ short Wp[2][16384];               // 64 KB  W1/W2 B-fragments
    __shared__ short Wep[4096];                  //  8 KB  WeW1 B-fragments (K=32)
    __shared__ short hrow[16][16 * HROW_STRIDE]; // 68 KB  per-wave node rows

    const int tid  = threadIdx.x;
    const int wave = tid >> 6;
    const int lane = tid & 63;
    const int m    = lane & 15;
    const int g    = lane >> 4;

    // pack W1/W2 B-fragments: Wp[l][s*64+lane] = B[k=kc*32+g*8+j][n=dt*16+m]
    for (int s = wave * 2; s < wave * 2 + 2; ++s) {
        const int dt = s >> 2, kc = s & 3;
        const int krow = kc * 32 + g * 8;
        const int col  = dt * 16 + m;
        short p1[8], p2[8];
        #pragma unroll
        for (int j = 0; j < 8; ++j) {
            p1[j] = f2bf(W1[(size_t)(krow + j) * DIM + col]);
            p2[j] = f2bf(W2[(size_t)(krow + j) * DIM + col]);
        }
        #pragma unroll
        for (int j = 0; j < 8; ++j) {
            Wp[0][(s * 64 + lane) * 8 + j] = p1[j];
            Wp[1][(s * 64 + lane) * 8 + j] = p2[j];
        }
    }
    // pack WeW1 B-fragments (K=32): Wep[dt*64+lane] = WeW1[k=g*8+j][n=dt*16+m]
    if (wave < 8) {
        const int dt = wave;
        const int col = dt * 16 + m;
        short pw[8];
        #pragma unroll
        for (int j = 0; j < 8; ++j) pw[j] = f2bf(wew1[(size_t)(g * 8 + j) * DIM + col]);
        #pragma unroll
        for (int j = 0; j < 8; ++j) Wep[(dt * 64 + lane) * 8 + j] = pw[j];
    }

    float b1v[8], b2v[8], gv[8], btv[8];
    #pragma unroll
    for (int dt = 0; dt < 8; ++dt) {
        const int d = dt * 16 + m;
        b1v[dt] = b1[d]; b2v[dt] = b2[d]; gv[dt] = gamma[d]; btv[dt] = beta[d];
    }
    const float epv = 1.0f + epsp[0];
    __syncthreads();

    short* myrow = &hrow[wave][0];
    const int ntiles = N_NODES / 16;             // 6250

    for (int tile = blockIdx.x * 16 + wave; tile < ntiles; tile += gridDim.x * 16) {
        const int nbase = tile * 16;

        // A-fragment of aggE: lane(m,g) takes aggE[nbase+m][g*8 .. g*8+8)
        bf16x8 afragE = *(const bf16x8*)&aggE[(size_t)(nbase + m) * EDIM + g * 8];

        // stage hrow = (1+eps)*x + aggX + deg*be as bf16 rows [16][128]
        #pragma unroll
        for (int r = 0; r < 8; ++r) {
            const int idx4 = r * 64 + lane;          // 512 quads = 16 nodes x 32
            const int node = idx4 >> 5, dq = idx4 & 31;
            const size_t goff = (size_t)(nbase + node) * DIM + dq * 4;
            float4 xv = *(const float4*)&x[goff];
            ushort4 au = *(const ushort4*)&aggX[goff];
            float4 bev = ((const float4*)be)[dq];
            float dgf = (float)(off[nbase + node + 1] - off[nbase + node]);
            short4 hv;
            hv.x = f2bf(epv * xv.x + bfu2f(au.x) + dgf * bev.x);
            hv.y = f2bf(epv * xv.y + bfu2f(au.y) + dgf * bev.y);
            hv.z = f2bf(epv * xv.z + bfu2f(au.z) + dgf * bev.z);
            hv.w = f2bf(epv * xv.w + bfu2f(au.w) + dgf * bev.w);
            *(short4*)&myrow[node * HROW_STRIDE + dq * 4] = hv;
        }
        __asm__ volatile("s_waitcnt lgkmcnt(0)" ::: "memory");

        // layer 1 = aggE@WeW1 (K=32 chunk) + hrow@W1 (K=128)
        f32x4 acc[8];
        #pragma unroll
        for (int dt = 0; dt < 8; ++dt) {
            bf16x8 bfrag = *(bf16x8*)&Wep[(dt * 64 + lane) * 8];
            acc[dt] = __builtin_amdgcn_mfma_f32_16x16x32_bf16(
                afragE, bfrag, (f32x4){0.f, 0.f, 0.f, 0.f}, 0, 0, 0);
        }
        #pragma unroll
        for (int kc = 0; kc < 4; ++kc) {
            bf16x8 afrag = *(bf16x8*)&myrow[m * HROW_STRIDE + kc * 32 + g * 8];
            #pragma unroll
            for (int dt = 0; dt < 8; ++dt) {
                bf16x8 bfrag = *(bf16x8*)&Wp[0][((dt * 4 + kc) * 64 + lane) * 8];
                acc[dt] = __builtin_amdgcn_mfma_f32_16x16x32_bf16(afrag, bfrag, acc[dt], 0, 0, 0);
            }
        }
        __asm__ volatile("s_waitcnt lgkmcnt(0)" ::: "memory");

        // relu(acc + b1) -> myrow (C-layout: node=g*4+q, dim=dt*16+m)
        #pragma unroll
        for (int dt = 0; dt < 8; ++dt)
            #pragma unroll
            for (int q = 0; q < 4; ++q) {
                float v = fmaxf(acc[dt][q] + b1v[dt], 0.f);
                myrow[(g * 4 + q) * HROW_STRIDE + dt * 16 + m] = f2bf(v);
            }
        __asm__ volatile("s_waitcnt lgkmcnt(0)" ::: "memory");

        // layer 2
        #pragma unroll
        for (int dt = 0; dt < 8; ++dt) acc[dt] = (f32x4){0.f, 0.f, 0.f, 0.f};
        #pragma unroll
        for (int kc = 0; kc < 4; ++kc) {
            bf16x8 afrag = *(bf16x8*)&myrow[m * HROW_STRIDE + kc * 32 + g * 8];
            #pragma unroll
            for (int dt = 0; dt < 8; ++dt) {
                bf16x8 bfrag = *(bf16x8*)&Wp[1][((dt * 4 + kc) * 64 + lane) * 8];
                acc[dt] = __builtin_amdgcn_mfma_f32_16x16x32_bf16(afrag, bfrag, acc[dt], 0, 0, 0);
            }
        }

        // bias + LayerNorm. Lane holds (dt,q): node g*4+q, dim dt*16+m.
        float s[4] = {0, 0, 0, 0}, ss[4] = {0, 0, 0, 0};
        #pragma unroll
        for (int dt = 0; dt < 8; ++dt)
            #pragma unroll
            for (int q = 0; q < 4; ++q) {
                float o = acc[dt][q] + b2v[dt];
                acc[dt][q] = o;
                s[q] += o; ss[q] += o * o;
            }
        #pragma unroll
        for (int mask = 1; mask < 16; mask <<= 1)
            #pragma unroll
            for (int q = 0; q < 4; ++q) {
                s[q]  += __shfl_xor(s[q], mask, 64);
                ss[q] += __shfl_xor(ss[q], mask, 64);
            }
        float mu[4], inv[4];
        #pragma unroll
        for (int q = 0; q < 4; ++q) {
            mu[q] = s[q] * (1.0f / DIM);
            float var = ss[q] * (1.0f / DIM) - mu[q] * mu[q];
            inv[q] = rsqrtf(var + 1e-5f);
        }
        #pragma unroll
        for (int dt = 0; dt < 8; ++dt)
            #pragma unroll
            for (int q = 0; q < 4; ++q) {
                const int node = nbase + g * 4 + q;
                out[(size_t)node * DIM + dt * 16 + m] =
                    (acc[dt][q] - mu[q]) * inv[q] * gv[dt] + btv[dt];
            }
    }
}

extern "C" void kernel_launch(void* const* d_in, const int* in_sizes, int n_in,
                              void* d_out, int out_size, void* d_ws, size_t ws_size,
                              hipStream_t stream) {
    const float* x     = (const float*)d_in[0];
    const int*   eidx  = (const int*)d_in[1];
    const float* eattr = (const float*)d_in[2];
    const float* We    = (const float*)d_in[3];
    const float* be    = (const float*)d_in[4];
    const float* W1    = (const float*)d_in[5];
    const float* b1    = (const float*)d_in[6];
    const float* W2    = (const float*)d_in[7];
    const float* b2v   = (const float*)d_in[8];
    const float* eps   = (const float*)d_in[9];
    const float* gamma = (const float*)d_in[10];
    const float* beta  = (const float*)d_in[11];
    float* out = (float*)d_out;

    char* ws = (char*)d_ws;
    unsigned short* aggX = (unsigned short*)(ws + AGGX_OFF);
    unsigned short* aggE = (unsigned short*)(ws + AGGE_OFF);
    int2*  csr  = (int2*)(ws + CSR_OFF);
    int*   off  = (int*)(ws + OFF_OFF);      // N+1 start offsets
    int*   cnt  = (int*)(ws + DEG_OFF);      // degree counts, then fill cursor
    int*   bsum = (int*)(ws + BSUM_OFF);
    float* wew1 = (float*)(ws + WEW1_OFF);
    unsigned short* xbf = (unsigned short*)(ws + XBF_OFF);
    const bool use_bf = (ws_size >= WS_NEED_XBF);

    hipMemsetAsync(cnt, 0, 400000, stream);
    compute_wew1<<<4, 1024, 0, stream>>>(We, W1, wew1);
    if (use_bf) cast_x_bf16<<<2048, 256, 0, stream>>>(x, xbf);
    count_deg<<<(N_EDGES + 255) / 256, 256, 0, stream>>>(eidx, cnt);
    scan_blocks<<<SCAN_NBLK, 1024, 0, stream>>>(cnt, off, bsum);
    scan_add2<<<SCAN_NBLK, 1024, 0, stream>>>(off, cnt, bsum);
    csr_fill<<<(N_EDGES + 255) / 256, 256, 0, stream>>>(eidx, cnt, csr);
    if (use_bf)
        gine_aggregate_t<1><<<2048, 256, 0, stream>>>(xbf, eattr, off, csr, aggX, aggE);
    else
        gine_aggregate_t<0><<<2048, 256, 0, stream>>>(x, eattr, off, csr, aggX, aggE);
    gine_mlp_fused<<<256, 1024, 0, stream>>>(x, aggX, aggE, off, wew1, be,
                                             W1, b1, W2, b2v, eps, gamma, beta, out);
}

// Round 6
// 348.849 us; speedup vs baseline: 1.0522x; 1.0522x over previous
//
#include <hip/hip_runtime.h>
#include <hip/hip_bf16.h>

#define N_NODES 100000
#define N_EDGES 600000
#define DIM 128
#define EDIM 32

typedef __attribute__((ext_vector_type(8))) short bf16x8;
typedef __attribute__((ext_vector_type(8))) short short8v;
typedef __attribute__((ext_vector_type(4))) float f32x4;

static __device__ __forceinline__ short f2bf(float v) {
    __hip_bfloat16 h = __float2bfloat16(v);
    return *(short*)&h;
}
static __device__ __forceinline__ float bfu2f(unsigned short u) {
    return __uint_as_float(((unsigned int)u) << 16);
}

// ---------------- workspace layout (bytes) ----------------
#define HROW_OFF  0ULL                       // bf16 N*128 = 25,600,000 (fused h rows)
#define AGGE_OFF  25600000ULL                // bf16 N*32  =  6,400,000
#define CSR_OFF   32000000ULL                // int2 E     =  4,800,000
#define OFF_OFF   36800000ULL                // int  N+1
#define DEG_OFF   37200008ULL                // int  N     (count, then fill-cursor)
#define BSUM_OFF  37600016ULL                // int  128
#define WEW1_OFF  37600528ULL                // f32  32*128 = 16,384 -> ends 37,616,912
#define XBF_OFF   37616912ULL                // bf16 N*128 = 25,600,000 -> 63,216,912
#define EPERM_OFF 63216912ULL                // bf16 E*32  = 38,400,000 -> 101,616,912
#define WS_TIER1  (XBF_OFF + 25600000ULL)    // proven available (round 3 ran bf path)
#define WS_TIER2  (EPERM_OFF + 38400000ULL)  // eattr-permute tier
#define SCAN_NBLK 98                         // ceil(100001/1024)

// ===========================================================================
// WeW1 = We @ W1  (32x128 f32). The aggE@We term enters layer 1 as
// aggE @ (We @ W1) by linearity (ReLU is applied after the full sum).
// ===========================================================================
__global__ __launch_bounds__(1024) void compute_wew1(
    const float* __restrict__ We, const float* __restrict__ W1,
    float* __restrict__ wew1) {
    const int idx = blockIdx.x * 1024 + threadIdx.x;   // 4 blocks -> 4096
    const int k = idx >> 7, d2 = idx & 127;
    float a = 0.f;
    #pragma unroll 8
    for (int d = 0; d < DIM; ++d)
        a += We[k * DIM + d] * W1[d * DIM + d2];       // We: uniform; W1: coalesced
    wew1[k * DIM + d2] = a;
}

// ===========================================================================
// x -> bf16 copy (streaming). Halves the per-edge gather footprint and leaves
// xbf warm in L3 for the aggregate.
// ===========================================================================
__global__ __launch_bounds__(256) void cast_x_bf16(
    const float* __restrict__ x, unsigned short* __restrict__ xbf) {
    const int total = N_NODES * DIM / 8;               // 1.6M chunks of 8
    for (int i = blockIdx.x * 256 + threadIdx.x; i < total; i += gridDim.x * 256) {
        float4 a = *(const float4*)&x[(size_t)i * 8];
        float4 b = *(const float4*)&x[(size_t)i * 8 + 4];
        short8v o;
        o[0] = f2bf(a.x); o[1] = f2bf(a.y); o[2] = f2bf(a.z); o[3] = f2bf(a.w);
        o[4] = f2bf(b.x); o[5] = f2bf(b.y); o[6] = f2bf(b.z); o[7] = f2bf(b.w);
        *(short8v*)&xbf[(size_t)i * 8] = o;
    }
}

// ===========================================================================
// CSR build
// ===========================================================================
__global__ void count_deg(const int* __restrict__ eidx, int* __restrict__ cnt) {
    int e = blockIdx.x * 256 + threadIdx.x;
    if (e < N_EDGES) atomicAdd(&cnt[eidx[e]], 1);
}

__global__ __launch_bounds__(1024) void scan_blocks(
    const int* __restrict__ cnt, int* __restrict__ off, int* __restrict__ bsum) {
    const int t = blockIdx.x * 1024 + threadIdx.x;
    const int lane = threadIdx.x & 63, wv = threadIdx.x >> 6;
    int v = (t < N_NODES) ? cnt[t] : 0;
    int s = v;
    #pragma unroll
    for (int o = 1; o < 64; o <<= 1) {
        int u = __shfl_up(s, o, 64);
        if (lane >= o) s += u;
    }
    __shared__ int wsum[16];
    if (lane == 63) wsum[wv] = s;
    __syncthreads();
    if (threadIdx.x == 0) {
        int a = 0;
        #pragma unroll
        for (int w = 0; w < 16; ++w) { int tmp = wsum[w]; wsum[w] = a; a += tmp; }
        bsum[blockIdx.x] = a;
    }
    __syncthreads();
    if (t < N_NODES) off[t] = s - v + wsum[wv];
}

// Adds the cross-block prefix (reduced in-kernel from bsum), writes the fill
// cursor copy, sets off[N]=E.
__global__ __launch_bounds__(1024) void scan_add2(
    int* __restrict__ off, int* __restrict__ cursor, const int* __restrict__ bsum) {
    __shared__ int pref;
    const int b = blockIdx.x;
    if (threadIdx.x < 64) {
        int v = 0;
        if ((int)threadIdx.x < b) v = bsum[threadIdx.x];
        const int i2 = threadIdx.x + 64;
        if (i2 < b) v += bsum[i2];
        #pragma unroll
        for (int o = 32; o >= 1; o >>= 1) v += __shfl_down(v, o, 64);
        if (threadIdx.x == 0) pref = v;
    }
    __syncthreads();
    const int t = b * 1024 + threadIdx.x;
    if (t < N_NODES) {
        const int val = off[t] + pref;
        off[t] = val;
        cursor[t] = val;
    } else if (t == N_NODES) {
        off[t] = N_EDGES;
    }
}

// PERME=1: additionally permutes eattr (sequential read by e — fully coalesced
// stream) into CSR order as bf16, converting the aggregate's 1-random-HBM-
// line-per-edge eattr gather into a 0.5-line streamed, L3-warm read.
// NOTE: EDIM=32 -> 8 float4 chunks per row (R5 bug: only 4 were copied,
// leaving columns 16..31 of eperm as workspace poison -> absmax blowup).
template <int PERME>
__global__ void csr_fill_t(const int* __restrict__ eidx, int* __restrict__ cursor,
                           int2* __restrict__ csr,
                           const float* __restrict__ eattr,
                           unsigned short* __restrict__ eperm) {
    int e = blockIdx.x * 256 + threadIdx.x;
    if (e < N_EDGES) {
        int i = eidx[e];
        int p = atomicAdd(&cursor[i], 1);
        csr[p] = make_int2(e, eidx[N_EDGES + e]);
        if constexpr (PERME) {
            #pragma unroll
            for (int c = 0; c < 8; ++c) {
                float4 v = *(const float4*)&eattr[(size_t)e * EDIM + c * 4];
                short4 o;
                o.x = f2bf(v.x); o.y = f2bf(v.y); o.z = f2bf(v.z); o.w = f2bf(v.w);
                *(short4*)&eperm[(size_t)p * EDIM + c * 4] = o;
            }
        }
    }
}

// ===========================================================================
// Aggregate + hrow fusion: HALF-WAVE (32 lanes) per node, 8-edge
// unconditional batch (clamped index, masked accumulate).
// Epilogue computes hrowG = (1+eps)*x + aggX + deg*be directly (saves the
// mlp kernel a 51.2 MB f32 x re-read + 25.6 MB aggX read).
// PERME=1 reads the bf16 CSR-ordered eattr copy (streamed, L3-warm);
// PERME=0 falls back to the f32 random gather.
// ===========================================================================
template <int PERME>
__global__ __launch_bounds__(256, 4) void gine_aggregate_t(
    const unsigned short* __restrict__ xbf,
    const void* __restrict__ eat,     // eperm (bf16) or eattr (f32)
    const int* __restrict__ off,      // N+1 start offsets
    const int2* __restrict__ csr,
    unsigned short* __restrict__ hrowG,
    unsigned short* __restrict__ aggE,
    const float* __restrict__ be,
    const float* __restrict__ epsp)
{
    const int l5 = threadIdx.x & 31;
    const int nhw = (gridDim.x * 256) >> 5;        // total half-waves
    int n = (blockIdx.x * 256 + threadIdx.x) >> 5; // my first node
    const float epv = 1.0f + epsp[0];
    const float4 bev = ((const float4*)be)[l5];    // L1-resident

    int s = off[n], e = off[n + 1];
    while (true) {
        const int n2 = n + nhw;                    // prefetch next node's extent
        int s2 = 0, e2 = 0;
        if (n2 < N_NODES) { s2 = off[n2]; e2 = off[n2 + 1]; }

        float a0 = 0.f, a1 = 0.f, a2 = 0.f, a3 = 0.f, ae = 0.f;
        for (int t0 = s; t0 < e; t0 += 8) {
            int pc[8];
            int2 cc[8];
            #pragma unroll
            for (int k = 0; k < 8; ++k) {
                pc[k] = min(t0 + k, e - 1);        // clamped: always valid
                cc[k] = csr[pc[k]];
            }
            ushort4 xv[8]; float ev[8];
            #pragma unroll
            for (int k = 0; k < 8; ++k) {
                xv[k] = *(const ushort4*)&xbf[(size_t)cc[k].y * DIM + l5 * 4];
                if constexpr (PERME)
                    ev[k] = bfu2f(((const unsigned short*)eat)[(size_t)pc[k] * EDIM + l5]);
                else
                    ev[k] = ((const float*)eat)[(size_t)cc[k].x * EDIM + l5];
            }
            #pragma unroll
            for (int k = 0; k < 8; ++k) {
                const float msk = (t0 + k < e) ? 1.f : 0.f;
                a0 += msk * bfu2f(xv[k].x); a1 += msk * bfu2f(xv[k].y);
                a2 += msk * bfu2f(xv[k].z); a3 += msk * bfu2f(xv[k].w);
                ae += msk * ev[k];
            }
        }
        // fused hrow: (1+eps)*x + aggX + deg*be  (own row read is coalesced)
        const float dgf = (float)(e - s);
        ushort4 xn = *(const ushort4*)&xbf[(size_t)n * DIM + l5 * 4];
        short4 hv;
        hv.x = f2bf(epv * bfu2f(xn.x) + a0 + dgf * bev.x);
        hv.y = f2bf(epv * bfu2f(xn.y) + a1 + dgf * bev.y);
        hv.z = f2bf(epv * bfu2f(xn.z) + a2 + dgf * bev.z);
        hv.w = f2bf(epv * bfu2f(xn.w) + a3 + dgf * bev.w);
        *(short4*)&hrowG[(size_t)n * DIM + l5 * 4] = hv;
        aggE[(size_t)n * EDIM + l5] = (unsigned short)f2bf(ae);

        if (n2 >= N_NODES) break;
        n = n2; s = s2; e = e2;
    }
}

// ===========================================================================
// Fused (aggE@WeW1) + MLP1 + MLP2 + LayerNorm, bf16 MFMA 16x16x32.
// layer1 = hrowG@W1 + aggE@(We@W1); hrowG precomputed by the aggregate.
// 1024 threads = 16 waves share W-fragment LDS caches.
// ===========================================================================
#define HROW_STRIDE 136

__global__ __launch_bounds__(1024) void gine_mlp_fused(
    const unsigned short* __restrict__ hrowG,
    const unsigned short* __restrict__ aggE,
    const float* __restrict__ wew1,
    const float* __restrict__ W1,
    const float* __restrict__ b1,
    const float* __restrict__ W2,
    const float* __restrict__ b2,
    const float* __restrict__ gamma,
    const float* __restrict__ beta,
    float* __restrict__ out)
{
    __shared__ short Wp[2][16384];               // 64 KB  W1/W2 B-fragments
    __shared__ short Wep[4096];                  //  8 KB  WeW1 B-fragments (K=32)
    __shared__ short hrow[16][16 * HROW_STRIDE]; // 68 KB  per-wave node rows

    const int tid  = threadIdx.x;
    const int wave = tid >> 6;
    const int lane = tid & 63;
    const int m    = lane & 15;
    const int g    = lane >> 4;

    // pack W1/W2 B-fragments: Wp[l][s*64+lane] = B[k=kc*32+g*8+j][n=dt*16+m]
    for (int s = wave * 2; s < wave * 2 + 2; ++s) {
        const int dt = s >> 2, kc = s & 3;
        const int krow = kc * 32 + g * 8;
        const int col  = dt * 16 + m;
        short p1[8], p2[8];
        #pragma unroll
        for (int j = 0; j < 8; ++j) {
            p1[j] = f2bf(W1[(size_t)(krow + j) * DIM + col]);
            p2[j] = f2bf(W2[(size_t)(krow + j) * DIM + col]);
        }
        #pragma unroll
        for (int j = 0; j < 8; ++j) {
            Wp[0][(s * 64 + lane) * 8 + j] = p1[j];
            Wp[1][(s * 64 + lane) * 8 + j] = p2[j];
        }
    }
    // pack WeW1 B-fragments (K=32): Wep[dt*64+lane] = WeW1[k=g*8+j][n=dt*16+m]
    if (wave < 8) {
        const int dt = wave;
        const int col = dt * 16 + m;
        short pw[8];
        #pragma unroll
        for (int j = 0; j < 8; ++j) pw[j] = f2bf(wew1[(size_t)(g * 8 + j) * DIM + col]);
        #pragma unroll
        for (int j = 0; j < 8; ++j) Wep[(dt * 64 + lane) * 8 + j] = pw[j];
    }

    float b1v[8], b2v[8], gv[8], btv[8];
    #pragma unroll
    for (int dt = 0; dt < 8; ++dt) {
        const int d = dt * 16 + m;
        b1v[dt] = b1[d]; b2v[dt] = b2[d]; gv[dt] = gamma[d]; btv[dt] = beta[d];
    }
    __syncthreads();

    short* myrow = &hrow[wave][0];
    const int ntiles = N_NODES / 16;             // 6250

    for (int tile = blockIdx.x * 16 + wave; tile < ntiles; tile += gridDim.x * 16) {
        const int nbase = tile * 16;

        // A-fragment of aggE: lane(m,g) takes aggE[nbase+m][g*8 .. g*8+8)
        bf16x8 afragE = *(const bf16x8*)&aggE[(size_t)(nbase + m) * EDIM + g * 8];

        // stage hrowG (bf16, precomputed) -> LDS: 16 nodes x 256 B = 4 KB
        #pragma unroll
        for (int r = 0; r < 4; ++r) {
            const int idx8 = r * 64 + lane;          // 256 chunks of 8 shorts
            const int node = idx8 >> 4, dc = idx8 & 15;
            short8v v = *(const short8v*)&hrowG[(size_t)(nbase + node) * DIM + dc * 8];
            *(short8v*)&myrow[node * HROW_STRIDE + dc * 8] = v;
        }
        __asm__ volatile("s_waitcnt lgkmcnt(0)" ::: "memory");

        // layer 1 = aggE@WeW1 (K=32 chunk) + hrow@W1 (K=128)
        f32x4 acc[8];
        #pragma unroll
        for (int dt = 0; dt < 8; ++dt) {
            bf16x8 bfrag = *(bf16x8*)&Wep[(dt * 64 + lane) * 8];
            acc[dt] = __builtin_amdgcn_mfma_f32_16x16x32_bf16(
                afragE, bfrag, (f32x4){0.f, 0.f, 0.f, 0.f}, 0, 0, 0);
        }
        #pragma unroll
        for (int kc = 0; kc < 4; ++kc) {
            bf16x8 afrag = *(bf16x8*)&myrow[m * HROW_STRIDE + kc * 32 + g * 8];
            #pragma unroll
            for (int dt = 0; dt < 8; ++dt) {
                bf16x8 bfrag = *(bf16x8*)&Wp[0][((dt * 4 + kc) * 64 + lane) * 8];
                acc[dt] = __builtin_amdgcn_mfma_f32_16x16x32_bf16(afrag, bfrag, acc[dt], 0, 0, 0);
            }
        }
        __asm__ volatile("s_waitcnt lgkmcnt(0)" ::: "memory");

        // relu(acc + b1) -> myrow (C-layout: node=g*4+q, dim=dt*16+m)
        #pragma unroll
        for (int dt = 0; dt < 8; ++dt)
            #pragma unroll
            for (int q = 0; q < 4; ++q) {
                float v = fmaxf(acc[dt][q] + b1v[dt], 0.f);
                myrow[(g * 4 + q) * HROW_STRIDE + dt * 16 + m] = f2bf(v);
            }
        __asm__ volatile("s_waitcnt lgkmcnt(0)" ::: "memory");

        // layer 2
        #pragma unroll
        for (int dt = 0; dt < 8; ++dt) acc[dt] = (f32x4){0.f, 0.f, 0.f, 0.f};
        #pragma unroll
        for (int kc = 0; kc < 4; ++kc) {
            bf16x8 afrag = *(bf16x8*)&myrow[m * HROW_STRIDE + kc * 32 + g * 8];
            #pragma unroll
            for (int dt = 0; dt < 8; ++dt) {
                bf16x8 bfrag = *(bf16x8*)&Wp[1][((dt * 4 + kc) * 64 + lane) * 8];
                acc[dt] = __builtin_amdgcn_mfma_f32_16x16x32_bf16(afrag, bfrag, acc[dt], 0, 0, 0);
            }
        }

        // bias + LayerNorm. Lane holds (dt,q): node g*4+q, dim dt*16+m.
        float s[4] = {0, 0, 0, 0}, ss[4] = {0, 0, 0, 0};
        #pragma unroll
        for (int dt = 0; dt < 8; ++dt)
            #pragma unroll
            for (int q = 0; q < 4; ++q) {
                float o = acc[dt][q] + b2v[dt];
                acc[dt][q] = o;
                s[q] += o; ss[q] += o * o;
            }
        #pragma unroll
        for (int mask = 1; mask < 16; mask <<= 1)
            #pragma unroll
            for (int q = 0; q < 4; ++q) {
                s[q]  += __shfl_xor(s[q], mask, 64);
                ss[q] += __shfl_xor(ss[q], mask, 64);
            }
        float mu[4], inv[4];
        #pragma unroll
        for (int q = 0; q < 4; ++q) {
            mu[q] = s[q] * (1.0f / DIM);
            float var = ss[q] * (1.0f / DIM) - mu[q] * mu[q];
            inv[q] = rsqrtf(var + 1e-5f);
        }
        #pragma unroll
        for (int dt = 0; dt < 8; ++dt)
            #pragma unroll
            for (int q = 0; q < 4; ++q) {
                const int node = nbase + g * 4 + q;
                out[(size_t)node * DIM + dt * 16 + m] =
                    (acc[dt][q] - mu[q]) * inv[q] * gv[dt] + btv[dt];
            }
    }
}

extern "C" void kernel_launch(void* const* d_in, const int* in_sizes, int n_in,
                              void* d_out, int out_size, void* d_ws, size_t ws_size,
                              hipStream_t stream) {
    const float* x     = (const float*)d_in[0];
    const int*   eidx  = (const int*)d_in[1];
    const float* eattr = (const float*)d_in[2];
    const float* We    = (const float*)d_in[3];
    const float* be    = (const float*)d_in[4];
    const float* W1    = (const float*)d_in[5];
    const float* b1    = (const float*)d_in[6];
    const float* W2    = (const float*)d_in[7];
    const float* b2v   = (const float*)d_in[8];
    const float* eps   = (const float*)d_in[9];
    const float* gamma = (const float*)d_in[10];
    const float* beta  = (const float*)d_in[11];
    float* out = (float*)d_out;

    char* ws = (char*)d_ws;
    unsigned short* hrowG = (unsigned short*)(ws + HROW_OFF);
    unsigned short* aggE  = (unsigned short*)(ws + AGGE_OFF);
    int2*  csr  = (int2*)(ws + CSR_OFF);
    int*   off  = (int*)(ws + OFF_OFF);      // N+1 start offsets
    int*   cnt  = (int*)(ws + DEG_OFF);      // degree counts, then fill cursor
    int*   bsum = (int*)(ws + BSUM_OFF);
    float* wew1 = (float*)(ws + WEW1_OFF);
    unsigned short* xbf   = (unsigned short*)(ws + XBF_OFF);
    unsigned short* eperm = (unsigned short*)(ws + EPERM_OFF);
    const bool use_perm = (ws_size >= WS_TIER2);   // tier1 proven by round 3

    (void)hipMemsetAsync(cnt, 0, 400000, stream);
    compute_wew1<<<4, 1024, 0, stream>>>(We, W1, wew1);
    cast_x_bf16<<<2048, 256, 0, stream>>>(x, xbf);
    count_deg<<<(N_EDGES + 255) / 256, 256, 0, stream>>>(eidx, cnt);
    scan_blocks<<<SCAN_NBLK, 1024, 0, stream>>>(cnt, off, bsum);
    scan_add2<<<SCAN_NBLK, 1024, 0, stream>>>(off, cnt, bsum);
    if (use_perm) {
        csr_fill_t<1><<<(N_EDGES + 255) / 256, 256, 0, stream>>>(eidx, cnt, csr, eattr, eperm);
        gine_aggregate_t<1><<<2048, 256, 0, stream>>>(xbf, eperm, off, csr, hrowG, aggE, be, eps);
    } else {
        csr_fill_t<0><<<(N_EDGES + 255) / 256, 256, 0, stream>>>(eidx, cnt, csr, eattr, eperm);
        gine_aggregate_t<0><<<2048, 256, 0, stream>>>(xbf, eattr, off, csr, hrowG, aggE, be, eps);
    }
    gine_mlp_fused<<<256, 1024, 0, stream>>>(hrowG, aggE, wew1,
                                             W1, b1, W2, b2v, gamma, beta, out);
}